// Round 7
// baseline (160.339 us; speedup 1.0000x reference)
//
#include <hip/hip_runtime.h>

// AnomalyAttention: B=16, L=512, H=8, E=D=64. f32 in/out, bf16 MFMA compute.
// Transposed formulation: S^T = K.Q^T (D: row=s, col=l), out^T = V^T.W^T.
// W (e,p) round-trips LDS as packed bf16 dwords with no bit-unpacking.
// out = [ g*(e@V)/E + (1-g)*(p@V)/(P+1e-8) ] / (Sf+1e-8); E,P = sums of
// truncated-bf16 e,p (consistent with MFMA operands). Prior exact-underflow
// band: |l-s|>=65 -> f32 zero. Uniform 8-tile loop (grid-wide lockstep; R5
// showed desync regresses L2 sharing). R7: register-prefetch pipelining —
// tile i+1's V/K global loads issue before tile i's compute phase, hiding
// global latency behind MFMA/exp (the serial chain was the R6 limiter).

#define B_ 16
#define L_ 512
#define H_ 8
#define KST 72   // K LDS row stride (shorts)
#define VST 72   // V^T LDS row stride (shorts)
#define WST 36   // W LDS row stride (dwords), 16 rows/wave

typedef __attribute__((ext_vector_type(8))) short bf16x8;
typedef __attribute__((ext_vector_type(4))) float f32x4;
union FR { bf16x8 v; unsigned u[4]; uint4 q4; };

static __device__ __forceinline__ unsigned fbits(float x){union{float f;unsigned u;}c;c.f=x;return c.u;}
static __device__ __forceinline__ float tvf(float x){union{unsigned u;float f;}c;c.u=fbits(x)&0xFFFF0000u;return c.f;}
// pack trunc-bf16(a) | trunc-bf16(b)<<16 in one v_perm_b32
static __device__ __forceinline__ unsigned pk2(float a,float b){return __builtin_amdgcn_perm(fbits(b),fbits(a),0x07060302u);}

__global__ __launch_bounds__(256,4) void anomaly_attn(
    const float* __restrict__ Q, const float* __restrict__ K,
    const float* __restrict__ V, const float* __restrict__ Sig,
    const float* __restrict__ Gate, float* __restrict__ Out)
{
  __shared__ unsigned short Klds[64*KST];   // 9216 B
  __shared__ unsigned short Vlds[64*VST];   // 9216 B (V^T, granule-swizzled)
  __shared__ unsigned We[4][16][WST];       // 9216 B packed e pairs (wave-private)
  __shared__ unsigned Wp[4][16][WST];       // 9216 B packed p pairs (wave-private)

  const int tid=threadIdx.x, lane=tid&63, wid=tid>>6, q=lane>>4, c=lane&15;
  const int idx=blockIdx.x, bh=idx&127, t=idx>>7, h=bh&7, b=bh>>3;
  const int l0w = t*64 + wid*16;            // wave's 16 l-rows: l = l0w + c
  const size_t bh_off = ((size_t)b*L_*H_ + h)*64;
  const float* __restrict__ Qb=Q+bh_off;
  const float* __restrict__ Kb=K+bh_off;
  const float* __restrict__ Vb=V+bh_off;

  const int kr=tid>>2, kcb=tid&3, srp=tid>>3, scb=tid&7;
  const int swz = (c&3)<<3;                 // W column XOR swizzle

  // ---- Q as B-operand frag: lane c -> l, quad*8+j -> e ----
  bf16x8 qf[2];
  {
    const float* qrow = Qb + (size_t)(l0w+c)*512;
    #pragma unroll
    for (int ks=0; ks<2; ++ks) {
      const float4 a = *(const float4*)(qrow + ks*32 + q*8);
      const float4 d4 = *(const float4*)(qrow + ks*32 + q*8 + 4);
      FR f;
      f.u[0]=pk2(a.x,a.y);  f.u[1]=pk2(a.z,a.w);
      f.u[2]=pk2(d4.x,d4.y); f.u[3]=pk2(d4.z,d4.w);
      qf[ks]=f.v;
    }
  }

  // ---- per-lane prior constants (row l = l0w + c) ----
  const float sgv = Sig[((size_t)b*L_ + l0w + c)*H_ + h];
  float sg = 1.f/(1.f+__expf(-5.f*sgv)) + 1e-5f;
  sg = exp2f(sg*1.5849625007211562f) - 1.f;          // 3^sg - 1
  const float invs = 0.3989422804014327f/sg;
  const float i2s2 = (0.5f/(sg*sg))*1.44269504088896f;

  float eP=0.f, pP=0.f;
  f32x4 accA[4], accB[4];
  #pragma unroll
  for (int n=0;n<4;++n){accA[n]=(f32x4)0.f;accB[n]=(f32x4)0.f;}

  // ---- prefetch registers + loaders ----
  float4 pv0, pv1, pv2, pv3;     // V tile (2 rows x 8 cols)
  float4 pk0, pk1, pk2r, pk3;    // K tile (1 row x 16 cols)
  const float* vpp = Vb + (size_t)(2*srp)*512 + scb*8;
  const float* kpp = Kb + (size_t)kr*512 + kcb*16;

  // prefetch tile 0 (tile 0 is always live)
  pv0=((const float4*)vpp)[0]; pv1=((const float4*)vpp)[1];
  pv2=((const float4*)(vpp+512))[0]; pv3=((const float4*)(vpp+512))[1];
  pk0=((const float4*)kpp)[0]; pk1=((const float4*)kpp)[1];
  pk2r=((const float4*)kpp)[2]; pk3=((const float4*)kpp)[3];

  for (int tile=0; tile<8; ++tile) {
    const int s0=tile*64;
    const bool live = tile<=t, diag = tile==t;   // block-uniform
    const int delta = s0 - l0w;                  // wave-uniform
    __syncthreads();   // barrier A: prior tile's K/V LDS reads complete

    { // ---- write prefetched V tile -> V^T bf16 pairs, granule-swizzled ----
      const float lo[8]={pv0.x,pv0.y,pv0.z,pv0.w,pv1.x,pv1.y,pv1.z,pv1.w};
      const float hi[8]={pv2.x,pv2.y,pv2.z,pv2.w,pv3.x,pv3.y,pv3.z,pv3.w};
      const int gp=(srp>>2)^scb, rpl=srp&3;
      #pragma unroll
      for (int i=0;i<8;++i){
        unsigned* p=(unsigned*)&Vlds[(scb*8+i)*VST + (gp<<3)];
        p[rpl]=pk2(lo[i],hi[i]);
      }
    }
    if (live) { // ---- write prefetched K tile -> rows [s][e] bf16 ----
      uint4 w0,w1;
      w0.x=pk2(pk0.x,pk0.y);  w0.y=pk2(pk0.z,pk0.w);
      w0.z=pk2(pk1.x,pk1.y);  w0.w=pk2(pk1.z,pk1.w);
      w1.x=pk2(pk2r.x,pk2r.y); w1.y=pk2(pk2r.z,pk2r.w);
      w1.z=pk2(pk3.x,pk3.y);  w1.w=pk2(pk3.z,pk3.w);
      uint4* dst=(uint4*)&Klds[kr*KST + kcb*16];
      dst[0]=w0; dst[1]=w1;
    }
    __syncthreads();   // barrier B: K/V LDS visible to all waves

    // ---- prefetch tile+1 (overlaps entire compute phase below) ----
    if (tile<7) {
      const float* vp = vpp + (size_t)(s0+64)*512;
      pv0=((const float4*)vp)[0]; pv1=((const float4*)vp)[1];
      pv2=((const float4*)(vp+512))[0]; pv3=((const float4*)(vp+512))[1];
      if (tile+1<=t) {
        const float* kp = kpp + (size_t)(s0+64)*512;
        pk0=((const float4*)kp)[0]; pk1=((const float4*)kp)[1];
        pk2r=((const float4*)kp)[2]; pk3=((const float4*)kp)[3];
      }
    }

    // ---- e path: scores S^T then packed bf16 into We (D-layout == B-layout) ----
    int ks2max = -1;
    if (live) {
      const int ntmax = diag ? wid : 3;         // s-chunks with any e!=0
      ks2max = diag ? (wid>>1) : 1;             // s-32-chunks for PV
      f32x4 sacc[4];
      #pragma unroll
      for (int nt=0;nt<4;++nt) if (nt<=ntmax) {
        f32x4 s=(f32x4)0.f;
        #pragma unroll
        for (int ks=0;ks<2;++ks){
          const bf16x8 kf=*(const bf16x8*)&Klds[(nt*16+c)*KST + ks*32 + q*8];
          s=__builtin_amdgcn_mfma_f32_16x16x32_bf16(kf,qf[ks],s,0,0,0); // A=K(m=s),B=Q(n=l)
        }
        sacc[nt]=s;
      }
      #pragma unroll
      for (int nt=0;nt<4;++nt) {
        if (nt<=ntmax) {
          float ev[4];
          #pragma unroll
          for (int r=0;r<4;++r) ev[r]=exp2f(sacc[nt][r]*0.180336880110323f); // exp(s/8)
          if (diag && nt==wid) {                 // per-element causal mask
            #pragma unroll
            for (int r=0;r<4;++r) if (4*q+r > c) ev[r]=0.f;
          }
          #pragma unroll
          for (int r=0;r<4;++r) eP += tvf(ev[r]);  // sum == MFMA operand
          uint2 w; w.x=pk2(ev[0],ev[1]); w.y=pk2(ev[2],ev[3]);
          *(uint2*)&We[wid][c][(nt*8+2*q)^swz]=w;
        } else if (nt <= 2*ks2max+1) {           // zero-fill read-covered chunk
          uint2 z; z.x=0u; z.y=0u;
          *(uint2*)&We[wid][c][(nt*8+2*q)^swz]=z;
        }
      }
    }

    // ---- p path: band-limited prior (exact f32 underflow outside) ----
    const bool bk0 = (delta    >= -95) && (delta    <= 79);
    const bool bk1 = (delta+32 >= -95) && (delta+32 <= 79);
    if (bk0||bk1) {
      #pragma unroll
      for (int nt=0;nt<4;++nt) {
        const bool need = (nt>>1) ? bk1 : bk0;
        if (need) {
          const int dbase = delta + nt*16;
          if (dbase>=-79 && dbase<=79) {
            float pv[4];
            #pragma unroll
            for (int r=0;r<4;++r){
              const float dd=(float)((c - 4*q - r) - dbase);  // l - s
              pv[r]=invs*exp2f(-dd*dd*i2s2);
              pP += tvf(pv[r]);
            }
            uint2 w; w.x=pk2(pv[0],pv[1]); w.y=pk2(pv[2],pv[3]);
            *(uint2*)&Wp[wid][c][(nt*8+2*q)^swz]=w;
          } else {
            uint2 z; z.x=0u; z.y=0u;
            *(uint2*)&Wp[wid][c][(nt*8+2*q)^swz]=z;
          }
        }
      }
    }
    asm volatile("s_waitcnt lgkmcnt(0)" ::: "memory");

    // ---- PV: A = V^T (m=d,k=s), B = W (k=s,n=l) ----
    FR ef[2], pf[2];
    #pragma unroll
    for (int k2=0;k2<2;++k2){
      const int col=(k2*16+4*q)^swz;
      if (k2<=ks2max)        ef[k2].q4 = *(const uint4*)&We[wid][c][col];
      if (k2 ? bk1 : bk0)    pf[k2].q4 = *(const uint4*)&Wp[wid][c][col];
    }
    #pragma unroll
    for (int nd=0;nd<4;++nd){
      const int d=nd*16+c, dg7=(d>>3)&7;
      #pragma unroll
      for (int k2=0;k2<2;++k2){
        const bool pb = k2 ? bk1 : bk0;
        if (k2<=ks2max || pb) {
          const int g2=((k2<<2)+q)^dg7;
          const bf16x8 vf=*(const bf16x8*)&Vlds[d*VST + (g2<<3)];
          if (k2<=ks2max) accA[nd]=__builtin_amdgcn_mfma_f32_16x16x32_bf16(vf,ef[k2].v,accA[nd],0,0,0);
          if (pb)         accB[nd]=__builtin_amdgcn_mfma_f32_16x16x32_bf16(vf,pf[k2].v,accB[nd],0,0,0);
        }
      }
    }
  }

  // ---- epilogue: quad reduce, per-lane scalars, float4 stores ----
  eP += __shfl_xor(eP,16,64); eP += __shfl_xor(eP,32,64);
  pP += __shfl_xor(pP,16,64); pP += __shfl_xor(pP,32,64);
  float g=Gate[h]; g=1.f/(1.f+__expf(-g));
  const float cA=g/eP;                       // E>0 (diagonal always live)
  const float cB=(1.f-g)/(pP+1e-8f);
  const float Sf=g+(1.f-g)*(pP/(pP+1e-8f));
  const float nf=1.f/(Sf+1e-8f);
  #pragma unroll
  for (int nd=0;nd<4;++nd){
    float4 o;
    o.x=(cA*accA[nd][0]+cB*accB[nd][0])*nf;
    o.y=(cA*accA[nd][1]+cB*accB[nd][1])*nf;
    o.z=(cA*accA[nd][2]+cB*accB[nd][2])*nf;
    o.w=(cA*accA[nd][3]+cB*accB[nd][3])*nf;
    *(float4*)&Out[bh_off + (size_t)(l0w+c)*512 + nd*16 + 4*q] = o;
  }
}

extern "C" void kernel_launch(void* const* d_in, const int* in_sizes, int n_in,
                              void* d_out, int out_size, void* d_ws, size_t ws_size,
                              hipStream_t stream) {
    const float* Q    = (const float*)d_in[0];
    const float* K    = (const float*)d_in[1];
    const float* V    = (const float*)d_in[2];
    const float* Sig  = (const float*)d_in[3];
    const float* Gate = (const float*)d_in[4];
    // d_in[5] = attn_mask: deterministic causal triu — not read.
    float* Out = (float*)d_out;

    dim3 grid(8 * B_ * H_);   // 1024 blocks: idx = t*128 + bh (XCD-affine)
    anomaly_attn<<<grid, 256, 0, stream>>>(Q, K, V, Sig, Gate, Out);
}

// Round 8
// 138.051 us; speedup vs baseline: 1.1615x; 1.1615x over previous
//
#include <hip/hip_runtime.h>

// AnomalyAttention: B=16, L=512, H=8, E=D=64. f32 in/out, bf16 MFMA compute.
// Transposed formulation: S^T = K.Q^T (D: row=s, col=l), out^T = V^T.W^T.
// W (e,p) round-trips LDS as packed bf16 dwords with no bit-unpacking.
// out = [ g*(e@V)/E + (1-g)*(p@V)/(P+1e-8) ] / (Sf+1e-8); E,P = sums of
// truncated-bf16 e,p (consistent with MFMA operands). Prior exact-underflow
// band: |l-s|>=65 -> f32 zero. Uniform 8-tile loop per unit (grid lockstep).
// R8: complementary-pair scheduling — 512 blocks, each runs unit (t,bh) then
// (7-t,bh). Per-block e-work = (t+1)+(8-t) = 9 tiles, EXACTLY uniform ->
// no straggler CUs regardless of dispatch policy. Inner body = R6 (best
// known); R7's register prefetch reverted (spilled: WRITE +18MB, 2x slower).

#define B_ 16
#define L_ 512
#define H_ 8
#define KST 72   // K LDS row stride (shorts)
#define VST 72   // V^T LDS row stride (shorts)
#define WST 36   // W LDS row stride (dwords), 16 rows/wave

typedef __attribute__((ext_vector_type(8))) short bf16x8;
typedef __attribute__((ext_vector_type(4))) float f32x4;
union FR { bf16x8 v; unsigned u[4]; uint4 q4; };

static __device__ __forceinline__ unsigned fbits(float x){union{float f;unsigned u;}c;c.f=x;return c.u;}
static __device__ __forceinline__ float tvf(float x){union{unsigned u;float f;}c;c.u=fbits(x)&0xFFFF0000u;return c.f;}
// pack trunc-bf16(a) | trunc-bf16(b)<<16 in one v_perm_b32
static __device__ __forceinline__ unsigned pk2(float a,float b){return __builtin_amdgcn_perm(fbits(b),fbits(a),0x07060302u);}

__global__ __launch_bounds__(256,4) void anomaly_attn(
    const float* __restrict__ Q, const float* __restrict__ K,
    const float* __restrict__ V, const float* __restrict__ Sig,
    const float* __restrict__ Gate, float* __restrict__ Out)
{
  __shared__ unsigned short Klds[64*KST];   // 9216 B
  __shared__ unsigned short Vlds[64*VST];   // 9216 B (V^T, granule-swizzled)
  __shared__ unsigned We[4][16][WST];       // 9216 B packed e pairs (wave-private)
  __shared__ unsigned Wp[4][16][WST];       // 9216 B packed p pairs (wave-private)

  const int tid=threadIdx.x, lane=tid&63, wid=tid>>6, q=lane>>4, c=lane&15;
  const int idx=blockIdx.x, bh=idx&127, p=idx>>7;   // p in 0..3
  const int h=bh&7, b=bh>>3;
  const size_t bh_off = ((size_t)b*L_*H_ + h)*64;
  const float* __restrict__ Qb=Q+bh_off;
  const float* __restrict__ Kb=K+bh_off;
  const float* __restrict__ Vb=V+bh_off;

  const int kr=tid>>2, kcb=tid&3, srp=tid>>3, scb=tid&7;
  const int swz = (c&3)<<3;                 // W column XOR swizzle

  float gth=Gate[h]; gth=1.f/(1.f+__expf(-gth));

  #pragma unroll 1
  for (int u=0; u<2; ++u) {
    const int t = u ? (7-p) : p;            // complementary pair: work sums to 9
    const int l0w = t*64 + wid*16;          // wave's 16 l-rows: l = l0w + c

    // ---- Q as B-operand frag: lane c -> l, quad*8+j -> e ----
    bf16x8 qf[2];
    {
      const float* qrow = Qb + (size_t)(l0w+c)*512;
      #pragma unroll
      for (int ks=0; ks<2; ++ks) {
        const float4 a = *(const float4*)(qrow + ks*32 + q*8);
        const float4 d4 = *(const float4*)(qrow + ks*32 + q*8 + 4);
        FR f;
        f.u[0]=pk2(a.x,a.y);  f.u[1]=pk2(a.z,a.w);
        f.u[2]=pk2(d4.x,d4.y); f.u[3]=pk2(d4.z,d4.w);
        qf[ks]=f.v;
      }
    }

    // ---- per-lane prior constants (row l = l0w + c) ----
    const float sgv = Sig[((size_t)b*L_ + l0w + c)*H_ + h];
    float sg = 1.f/(1.f+__expf(-5.f*sgv)) + 1e-5f;
    sg = exp2f(sg*1.5849625007211562f) - 1.f;          // 3^sg - 1
    const float invs = 0.3989422804014327f/sg;
    const float i2s2 = (0.5f/(sg*sg))*1.44269504088896f;

    float eP=0.f, pP=0.f;
    f32x4 accA[4], accB[4];
    #pragma unroll
    for (int n=0;n<4;++n){accA[n]=(f32x4)0.f;accB[n]=(f32x4)0.f;}

    for (int tile=0; tile<8; ++tile) {
      const int s0=tile*64;
      const bool live = tile<=t, diag = tile==t;   // block-uniform
      const int delta = s0 - l0w;                  // wave-uniform
      __syncthreads();   // barrier A: prior tile's (or unit's) LDS reads done
      { // ---- V stage (all tiles: uniform lockstep): V^T bf16 pairs ----
        const float* vp = Vb + (size_t)(s0+2*srp)*512 + scb*8;
        const float4 va0=((const float4*)vp)[0], va1=((const float4*)vp)[1];
        const float4 vb0=((const float4*)(vp+512))[0], vb1=((const float4*)(vp+512))[1];
        const float lo[8]={va0.x,va0.y,va0.z,va0.w,va1.x,va1.y,va1.z,va1.w};
        const float hi[8]={vb0.x,vb0.y,vb0.z,vb0.w,vb1.x,vb1.y,vb1.z,vb1.w};
        const int gp=(srp>>2)^scb, rpl=srp&3;
        #pragma unroll
        for (int i=0;i<8;++i){
          unsigned* pp=(unsigned*)&Vlds[(scb*8+i)*VST + (gp<<3)];
          pp[rpl]=pk2(lo[i],hi[i]);
        }
      }
      if (live) { // ---- K stage: rows [s][e] bf16 ----
        const float* kp = Kb + (size_t)(s0+kr)*512 + kcb*16;
        const float4 ka=((const float4*)kp)[0], kb2=((const float4*)kp)[1];
        const float4 kc2=((const float4*)kp)[2], kd2=((const float4*)kp)[3];
        uint4 w0,w1;
        w0.x=pk2(ka.x,ka.y);  w0.y=pk2(ka.z,ka.w);
        w0.z=pk2(kb2.x,kb2.y); w0.w=pk2(kb2.z,kb2.w);
        w1.x=pk2(kc2.x,kc2.y); w1.y=pk2(kc2.z,kc2.w);
        w1.z=pk2(kd2.x,kd2.y); w1.w=pk2(kd2.z,kd2.w);
        uint4* dst=(uint4*)&Klds[kr*KST + kcb*16];
        dst[0]=w0; dst[1]=w1;
      }
      __syncthreads();   // barrier B: K/V LDS visible to all waves

      // ---- e path: scores S^T then packed bf16 into We ----
      int ks2max = -1;
      if (live) {
        const int ntmax = diag ? wid : 3;         // s-chunks with any e!=0
        ks2max = diag ? (wid>>1) : 1;             // s-32-chunks for PV
        f32x4 sacc[4];
        #pragma unroll
        for (int nt=0;nt<4;++nt) if (nt<=ntmax) {
          f32x4 s=(f32x4)0.f;
          #pragma unroll
          for (int ks=0;ks<2;++ks){
            const bf16x8 kf=*(const bf16x8*)&Klds[(nt*16+c)*KST + ks*32 + q*8];
            s=__builtin_amdgcn_mfma_f32_16x16x32_bf16(kf,qf[ks],s,0,0,0); // A=K(m=s),B=Q(n=l)
          }
          sacc[nt]=s;
        }
        #pragma unroll
        for (int nt=0;nt<4;++nt) {
          if (nt<=ntmax) {
            float ev[4];
            #pragma unroll
            for (int r=0;r<4;++r) ev[r]=exp2f(sacc[nt][r]*0.180336880110323f); // exp(s/8)
            if (diag && nt==wid) {                 // per-element causal mask
              #pragma unroll
              for (int r=0;r<4;++r) if (4*q+r > c) ev[r]=0.f;
            }
            #pragma unroll
            for (int r=0;r<4;++r) eP += tvf(ev[r]);  // sum == MFMA operand
            uint2 w; w.x=pk2(ev[0],ev[1]); w.y=pk2(ev[2],ev[3]);
            *(uint2*)&We[wid][c][(nt*8+2*q)^swz]=w;
          } else if (nt <= 2*ks2max+1) {           // zero-fill read-covered chunk
            uint2 z; z.x=0u; z.y=0u;
            *(uint2*)&We[wid][c][(nt*8+2*q)^swz]=z;
          }
        }
      }

      // ---- p path: band-limited prior (exact f32 underflow outside) ----
      const bool bk0 = (delta    >= -95) && (delta    <= 79);
      const bool bk1 = (delta+32 >= -95) && (delta+32 <= 79);
      if (bk0||bk1) {
        #pragma unroll
        for (int nt=0;nt<4;++nt) {
          const bool need = (nt>>1) ? bk1 : bk0;
          if (need) {
            const int dbase = delta + nt*16;
            if (dbase>=-79 && dbase<=79) {
              float pv[4];
              #pragma unroll
              for (int r=0;r<4;++r){
                const float dd=(float)((c - 4*q - r) - dbase);  // l - s
                pv[r]=invs*exp2f(-dd*dd*i2s2);
                pP += tvf(pv[r]);
              }
              uint2 w; w.x=pk2(pv[0],pv[1]); w.y=pk2(pv[2],pv[3]);
              *(uint2*)&Wp[wid][c][(nt*8+2*q)^swz]=w;
            } else {
              uint2 z; z.x=0u; z.y=0u;
              *(uint2*)&Wp[wid][c][(nt*8+2*q)^swz]=z;
            }
          }
        }
      }
      asm volatile("s_waitcnt lgkmcnt(0)" ::: "memory");

      // ---- PV: A = V^T (m=d,k=s), B = W (k=s,n=l) ----
      FR ef[2], pf[2];
      #pragma unroll
      for (int k2=0;k2<2;++k2){
        const int col=(k2*16+4*q)^swz;
        if (k2<=ks2max)        ef[k2].q4 = *(const uint4*)&We[wid][c][col];
        if (k2 ? bk1 : bk0)    pf[k2].q4 = *(const uint4*)&Wp[wid][c][col];
      }
      #pragma unroll
      for (int nd=0;nd<4;++nd){
        const int d=nd*16+c, dg7=(d>>3)&7;
        #pragma unroll
        for (int k2=0;k2<2;++k2){
          const bool pb = k2 ? bk1 : bk0;
          if (k2<=ks2max || pb) {
            const int g2=((k2<<2)+q)^dg7;
            const bf16x8 vf=*(const bf16x8*)&Vlds[d*VST + (g2<<3)];
            if (k2<=ks2max) accA[nd]=__builtin_amdgcn_mfma_f32_16x16x32_bf16(vf,ef[k2].v,accA[nd],0,0,0);
            if (pb)         accB[nd]=__builtin_amdgcn_mfma_f32_16x16x32_bf16(vf,pf[k2].v,accB[nd],0,0,0);
          }
        }
      }
    }

    // ---- epilogue: quad reduce, per-lane scalars, float4 stores ----
    eP += __shfl_xor(eP,16,64); eP += __shfl_xor(eP,32,64);
    pP += __shfl_xor(pP,16,64); pP += __shfl_xor(pP,32,64);
    const float cA=gth/eP;                     // E>0 (diagonal always live)
    const float cB=(1.f-gth)/(pP+1e-8f);
    const float Sf=gth+(1.f-gth)*(pP/(pP+1e-8f));
    const float nf=1.f/(Sf+1e-8f);
    #pragma unroll
    for (int nd=0;nd<4;++nd){
      float4 o;
      o.x=(cA*accA[nd][0]+cB*accB[nd][0])*nf;
      o.y=(cA*accA[nd][1]+cB*accB[nd][1])*nf;
      o.z=(cA*accA[nd][2]+cB*accB[nd][2])*nf;
      o.w=(cA*accA[nd][3]+cB*accB[nd][3])*nf;
      *(float4*)&Out[bh_off + (size_t)(l0w+c)*512 + nd*16 + 4*q] = o;
    }
  }
}

extern "C" void kernel_launch(void* const* d_in, const int* in_sizes, int n_in,
                              void* d_out, int out_size, void* d_ws, size_t ws_size,
                              hipStream_t stream) {
    const float* Q    = (const float*)d_in[0];
    const float* K    = (const float*)d_in[1];
    const float* V    = (const float*)d_in[2];
    const float* Sig  = (const float*)d_in[3];
    const float* Gate = (const float*)d_in[4];
    // d_in[5] = attn_mask: deterministic causal triu — not read.
    float* Out = (float*)d_out;

    dim3 grid(4 * B_ * H_);   // 512 blocks: idx = p*128 + bh; units (p, 7-p)
    anomaly_attn<<<grid, 256, 0, stream>>>(Q, K, V, Sig, Gate, Out);
}

// Round 9
// 122.243 us; speedup vs baseline: 1.3116x; 1.1293x over previous
//
#include <hip/hip_runtime.h>

// AnomalyAttention: B=16, L=512, H=8, E=D=64. f32 in/out, bf16 MFMA compute.
// Transposed formulation: S^T = K.Q^T (D: row=s, col=l), out^T = V^T.W^T.
// e round-trips LDS as packed bf16 dwords (writer D-layout == reader B-layout,
// no bit-unpacking). R9: prior p is computed DIRECTLY in B-operand layout per
// lane (it depends only on l-s and per-l sigma; lane owns row l=c) -> Wp LDS
// array eliminated. V staging skipped on dead tiles (tile>t+1: e masked, p==0
// by exact f32 underflow) while keeping a uniform 8-iteration loop with
// identical barrier cadence (R5: iteration-count desync regresses; R8: block
// concurrency beats tail uniformity -> grid 1024, 4 blocks/CU).
// out = [ g*(e@V)/E + (1-g)*(p@V)/(P+1e-8) ] / (Sf+1e-8); E,P = sums of
// truncated-bf16 e,p (exactly the MFMA operands).

#define B_ 16
#define L_ 512
#define H_ 8
#define KST 72   // K LDS row stride (shorts)
#define VST 72   // V^T LDS row stride (shorts)
#define WST 36   // We LDS row stride (dwords), 16 rows/wave

typedef __attribute__((ext_vector_type(8))) short bf16x8;
typedef __attribute__((ext_vector_type(4))) float f32x4;
union FR { bf16x8 v; unsigned u[4]; uint4 q4; };

static __device__ __forceinline__ unsigned fbits(float x){union{float f;unsigned u;}c;c.f=x;return c.u;}
static __device__ __forceinline__ float tvf(float x){union{unsigned u;float f;}c;c.u=fbits(x)&0xFFFF0000u;return c.f;}
// pack trunc-bf16(a) | trunc-bf16(b)<<16 in one v_perm_b32
static __device__ __forceinline__ unsigned pk2(float a,float b){return __builtin_amdgcn_perm(fbits(b),fbits(a),0x07060302u);}

__global__ __launch_bounds__(256,4) void anomaly_attn(
    const float* __restrict__ Q, const float* __restrict__ K,
    const float* __restrict__ V, const float* __restrict__ Sig,
    const float* __restrict__ Gate, float* __restrict__ Out)
{
  __shared__ unsigned short Klds[64*KST];   // 9216 B
  __shared__ unsigned short Vlds[64*VST];   // 9216 B (V^T, granule-swizzled)
  __shared__ unsigned We[4][16][WST];       // 9216 B packed e pairs (wave-private)

  const int tid=threadIdx.x, lane=tid&63, wid=tid>>6, q=lane>>4, c=lane&15;
  const int idx=blockIdx.x, bh=idx&127, t=idx>>7, h=bh&7, b=bh>>3;
  const int l0w = t*64 + wid*16;            // wave's 16 l-rows: l = l0w + c
  const size_t bh_off = ((size_t)b*L_*H_ + h)*64;
  const float* __restrict__ Qb=Q+bh_off;
  const float* __restrict__ Kb=K+bh_off;
  const float* __restrict__ Vb=V+bh_off;

  const int kr=tid>>2, kcb=tid&3, srp=tid>>3, scb=tid&7;
  const int swz = (c&3)<<3;                 // We column XOR swizzle

  // ---- Q as B-operand frag: lane c -> l, quad*8+j -> e ----
  bf16x8 qf[2];
  {
    const float* qrow = Qb + (size_t)(l0w+c)*512;
    #pragma unroll
    for (int ks=0; ks<2; ++ks) {
      const float4 a = *(const float4*)(qrow + ks*32 + q*8);
      const float4 d4 = *(const float4*)(qrow + ks*32 + q*8 + 4);
      FR f;
      f.u[0]=pk2(a.x,a.y);  f.u[1]=pk2(a.z,a.w);
      f.u[2]=pk2(d4.x,d4.y); f.u[3]=pk2(d4.z,d4.w);
      qf[ks]=f.v;
    }
  }

  // ---- per-lane prior constants (row l = l0w + c) ----
  const float sgv = Sig[((size_t)b*L_ + l0w + c)*H_ + h];
  float sg = 1.f/(1.f+__expf(-5.f*sgv)) + 1e-5f;
  sg = exp2f(sg*1.5849625007211562f) - 1.f;          // 3^sg - 1
  const float invs = 0.3989422804014327f/sg;
  const float i2s2 = (0.5f/(sg*sg))*1.44269504088896f;

  float eP=0.f, pP=0.f;
  f32x4 accA[4], accB[4];
  #pragma unroll
  for (int n=0;n<4;++n){accA[n]=(f32x4)0.f;accB[n]=(f32x4)0.f;}

  for (int tile=0; tile<8; ++tile) {
    const int s0=tile*64;
    const bool live = tile<=t, diag = tile==t;   // block-uniform
    const int delta = s0 - l0w;                  // wave-uniform
    // prior band per 32-col chunk (s-l range vs |l-s|<=64 support)
    const bool bk0 = (delta    >= -95) && (delta    <= 79);
    const bool bk1 = (delta+32 >= -95) && (delta+32 <= 79);
    const bool vneed = live || bk0 || bk1;       // dead tiles skip V stage
    __syncthreads();   // barrier A: prior tile's K/V LDS reads complete

    if (vneed) { // ---- V stage: V^T bf16 pairs, granule-swizzled ----
      const float* vp = Vb + (size_t)(s0+2*srp)*512 + scb*8;
      const float4 va0=((const float4*)vp)[0], va1=((const float4*)vp)[1];
      const float4 vb0=((const float4*)(vp+512))[0], vb1=((const float4*)(vp+512))[1];
      const float lo[8]={va0.x,va0.y,va0.z,va0.w,va1.x,va1.y,va1.z,va1.w};
      const float hi[8]={vb0.x,vb0.y,vb0.z,vb0.w,vb1.x,vb1.y,vb1.z,vb1.w};
      const int gp=(srp>>2)^scb, rpl=srp&3;
      #pragma unroll
      for (int i=0;i<8;++i){
        unsigned* pp=(unsigned*)&Vlds[(scb*8+i)*VST + (gp<<3)];
        pp[rpl]=pk2(lo[i],hi[i]);
      }
    }
    if (live) { // ---- K stage: rows [s][e] bf16 ----
      const float* kp = Kb + (size_t)(s0+kr)*512 + kcb*16;
      const float4 ka=((const float4*)kp)[0], kb2=((const float4*)kp)[1];
      const float4 kc2=((const float4*)kp)[2], kd2=((const float4*)kp)[3];
      uint4 w0,w1;
      w0.x=pk2(ka.x,ka.y);  w0.y=pk2(ka.z,ka.w);
      w0.z=pk2(kb2.x,kb2.y); w0.w=pk2(kb2.z,kb2.w);
      w1.x=pk2(kc2.x,kc2.y); w1.y=pk2(kc2.z,kc2.w);
      w1.z=pk2(kd2.x,kd2.y); w1.w=pk2(kd2.z,kd2.w);
      uint4* dst=(uint4*)&Klds[kr*KST + kcb*16];
      dst[0]=w0; dst[1]=w1;
    }
    __syncthreads();   // barrier B: K/V LDS visible to all waves

    // ---- e path: scores S^T then packed bf16 into We (D-layout == B-layout) ----
    int ks2max = -1;
    if (live) {
      const int ntmax = diag ? wid : 3;         // s-chunks with any e!=0
      ks2max = diag ? (wid>>1) : 1;             // s-32-chunks for PV
      f32x4 sacc[4];
      #pragma unroll
      for (int nt=0;nt<4;++nt) if (nt<=ntmax) {
        f32x4 s=(f32x4)0.f;
        #pragma unroll
        for (int ks=0;ks<2;++ks){
          const bf16x8 kf=*(const bf16x8*)&Klds[(nt*16+c)*KST + ks*32 + q*8];
          s=__builtin_amdgcn_mfma_f32_16x16x32_bf16(kf,qf[ks],s,0,0,0); // A=K(m=s),B=Q(n=l)
        }
        sacc[nt]=s;
      }
      #pragma unroll
      for (int nt=0;nt<4;++nt) {
        if (nt<=ntmax) {
          float ev[4];
          #pragma unroll
          for (int r=0;r<4;++r) ev[r]=exp2f(sacc[nt][r]*0.180336880110323f); // exp(s/8)
          if (diag && nt==wid) {                 // per-element causal mask
            #pragma unroll
            for (int r=0;r<4;++r) if (4*q+r > c) ev[r]=0.f;
          }
          #pragma unroll
          for (int r=0;r<4;++r) eP += tvf(ev[r]);  // sum == MFMA operand
          uint2 w; w.x=pk2(ev[0],ev[1]); w.y=pk2(ev[2],ev[3]);
          *(uint2*)&We[wid][c][(nt*8+2*q)^swz]=w;
        } else if (nt <= 2*ks2max+1) {           // zero-fill read-covered chunk
          uint2 z; z.x=0u; z.y=0u;
          *(uint2*)&We[wid][c][(nt*8+2*q)^swz]=z;
        }
      }
    }
    asm volatile("s_waitcnt lgkmcnt(0)" ::: "memory");

    // ---- PV frags: e from We; p computed directly in B layout ----
    FR ef[2], pf[2];
    #pragma unroll
    for (int k2=0;k2<2;++k2){
      if (k2<=ks2max) ef[k2].q4 = *(const uint4*)&We[wid][c][(k2*16+4*q)^swz];
      if (k2 ? bk1 : bk0) {
        float pv[8];
        #pragma unroll
        for (int j=0;j<8;++j){
          const float dd=(float)(c - k2*32 - q*8 - j - delta);  // l - s
          pv[j]=invs*exp2f(-dd*dd*i2s2);
          pP += tvf(pv[j]);
        }
        pf[k2].u[0]=pk2(pv[0],pv[1]); pf[k2].u[1]=pk2(pv[2],pv[3]);
        pf[k2].u[2]=pk2(pv[4],pv[5]); pf[k2].u[3]=pk2(pv[6],pv[7]);
      }
    }
    // ---- PV: A = V^T (m=d,k=s), B = W (k=s,n=l) ----
    #pragma unroll
    for (int nd=0;nd<4;++nd){
      const int d=nd*16+c, dg7=(d>>3)&7;
      #pragma unroll
      for (int k2=0;k2<2;++k2){
        const bool pb = k2 ? bk1 : bk0;
        if (k2<=ks2max || pb) {
          const int g2=((k2<<2)+q)^dg7;
          const bf16x8 vf=*(const bf16x8*)&Vlds[d*VST + (g2<<3)];
          if (k2<=ks2max) accA[nd]=__builtin_amdgcn_mfma_f32_16x16x32_bf16(vf,ef[k2].v,accA[nd],0,0,0);
          if (pb)         accB[nd]=__builtin_amdgcn_mfma_f32_16x16x32_bf16(vf,pf[k2].v,accB[nd],0,0,0);
        }
      }
    }
    asm volatile("s_waitcnt lgkmcnt(0)" ::: "memory");
  }

  // ---- epilogue: quad reduce, per-lane scalars, float4 stores ----
  eP += __shfl_xor(eP,16,64); eP += __shfl_xor(eP,32,64);
  pP += __shfl_xor(pP,16,64); pP += __shfl_xor(pP,32,64);
  float g=Gate[h]; g=1.f/(1.f+__expf(-g));
  const float cA=g/eP;                       // E>0 (diagonal always live)
  const float cB=(1.f-g)/(pP+1e-8f);
  const float Sf=g+(1.f-g)*(pP/(pP+1e-8f));
  const float nf=1.f/(Sf+1e-8f);
  #pragma unroll
  for (int nd=0;nd<4;++nd){
    float4 o;
    o.x=(cA*accA[nd][0]+cB*accB[nd][0])*nf;
    o.y=(cA*accA[nd][1]+cB*accB[nd][1])*nf;
    o.z=(cA*accA[nd][2]+cB*accB[nd][2])*nf;
    o.w=(cA*accA[nd][3]+cB*accB[nd][3])*nf;
    *(float4*)&Out[bh_off + (size_t)(l0w+c)*512 + nd*16 + 4*q] = o;
  }
}

extern "C" void kernel_launch(void* const* d_in, const int* in_sizes, int n_in,
                              void* d_out, int out_size, void* d_ws, size_t ws_size,
                              hipStream_t stream) {
    const float* Q    = (const float*)d_in[0];
    const float* K    = (const float*)d_in[1];
    const float* V    = (const float*)d_in[2];
    const float* Sig  = (const float*)d_in[3];
    const float* Gate = (const float*)d_in[4];
    // d_in[5] = attn_mask: deterministic causal triu — not read.
    float* Out = (float*)d_out;

    dim3 grid(8 * B_ * H_);   // 1024 blocks: idx = t*128 + bh (XCD-affine)
    anomaly_attn<<<grid, 256, 0, stream>>>(Q, K, V, Sig, Gate, Out);
}